// Round 2
// baseline (1360.339 us; speedup 1.0000x reference)
//
#include <hip/hip_runtime.h>

#define NN 64
#define NI 6
#define TT 1024
#define BB 1024
#define TB (TT * BB)
#define NSCALE 0.13416407864998738f        // sqrt(2/alpha) * sigma
#define ARNSCALE 0.013416407864998739f     // alpha * NSCALE

__device__ __forceinline__ float rdlane(float v, int l) {
    return __int_as_float(__builtin_amdgcn_readlane(__float_as_int(v), l));
}

// 256 threads = 4 independent waves; wave = 1 batch, lane = neuron.
// NO __syncthreads anywhere -> no vmcnt drains on the recurrence path.
__global__ __launch_bounds__(256, 1) void latent_rnn(
    const float* __restrict__ u,      // (6, T, B)
    const float* __restrict__ rn,     // (64, T, B)
    const float* __restrict__ inn,    // (6, T, B)
    const float* __restrict__ Winp,   // (64, 6)
    const float* __restrict__ Wrec,   // (64, 64)
    const float* __restrict__ Wout,   // (2, 64)
    float* __restrict__ states,       // (64, T, B)
    float* __restrict__ outputs)      // (2, T, B)
{
    // XCD swizzle: 256 blocks, 32 consecutive logical blocks (=128 batches) per XCD
    const int hw = blockIdx.x;
    const int lb = (hw & 7) * 32 + (hw >> 3);
    const int tid = threadIdx.x;
    const int n   = tid & 63;   // lane = neuron
    const int wid = tid >> 6;   // wave = batch within block
    const int b   = lb * 4 + wid;

    // ---- per-lane weights in registers ----
    float wr[NN];
#pragma unroll
    for (int k = 0; k < NN; k += 4) {
        float4 w4 = *reinterpret_cast<const float4*>(Wrec + n * NN + k);
        wr[k] = w4.x; wr[k + 1] = w4.y; wr[k + 2] = w4.z; wr[k + 3] = w4.w;
    }
    float wiu[NI], win[NI];
#pragma unroll
    for (int i = 0; i < NI; ++i) {
        wiu[i] = Winp[n * NI + i];
        win[i] = NSCALE * wiu[i];
    }
    const float wo0 = Wout[n];
    const float wo1 = Wout[NN + n];

    // combined u/inn gather: lanes 0-5 -> u rows, lanes 6-11 -> inn rows, rest dummy
    const float* gsrc = (n < NI)     ? (u   + (size_t)n * TB + b)
                      : (n < 2 * NI) ? (inn + (size_t)(n - NI) * TB + b)
                                     : (u + b);
    const float* rsrc = rn + (size_t)n * TB + b;
    float* sdst = states + (size_t)n * TB + b;

    // ---- t = 0 rows are zero ----
    sdst[0] = 0.0f;
    if (n < 2) outputs[(size_t)n * TB + b] = 0.0f;

    // ---- prefetch depth 4 (static slots only!) ----
    float rnb[4], gbf[4];
#pragma unroll
    for (int d = 0; d < 4; ++d) {
        rnb[d] = rsrc[(size_t)d * BB];
        gbf[d] = gsrc[(size_t)d * BB];
    }

    float x = 0.0f;

#define STEP(tcur, slot)                                                      \
    do {                                                                      \
        const float rcur = rnb[slot];                                         \
        const float gcur = gbf[slot];                                         \
        int tp = (tcur) + 4; if (tp > TT - 1) tp = TT - 1;                    \
        rnb[slot] = rsrc[(size_t)tp * BB];                                    \
        gbf[slot] = gsrc[(size_t)tp * BB];                                    \
        float a0 = 0.f, a1 = 0.f, a2 = 0.f, a3 = 0.f;                         \
        _Pragma("unroll")                                                     \
        for (int i = 0; i < NI; ++i) {                                        \
            a0 = fmaf(rdlane(gcur, i),      wiu[i], a0);                      \
            a1 = fmaf(rdlane(gcur, NI + i), win[i], a1);                      \
        }                                                                     \
        _Pragma("unroll")                                                     \
        for (int k = 0; k < NN; k += 4) {                                     \
            a0 = fmaf(rdlane(x, k + 0), wr[k + 0], a0);                       \
            a1 = fmaf(rdlane(x, k + 1), wr[k + 1], a1);                       \
            a2 = fmaf(rdlane(x, k + 2), wr[k + 2], a2);                       \
            a3 = fmaf(rdlane(x, k + 3), wr[k + 3], a3);                       \
        }                                                                     \
        const float pre = (a0 + a1) + (a2 + a3);                              \
        const float act = fmaxf(pre, 0.0f);                                   \
        x = 0.9f * x + 0.1f * act + ARNSCALE * rcur;                          \
        sdst[(size_t)((tcur) + 1) * BB] = x;                                  \
        float p0 = x * wo0, p1 = x * wo1;                                     \
        _Pragma("unroll")                                                     \
        for (int m = 1; m < 64; m <<= 1) {                                    \
            p0 += __shfl_xor(p0, m);                                          \
            p1 += __shfl_xor(p1, m);                                          \
        }                                                                     \
        if (n < 2)                                                            \
            outputs[(size_t)n * TB + (size_t)((tcur) + 1) * BB + b] =         \
                (n == 0) ? p0 : p1;                                           \
    } while (0)

    // 1023 steps = 255*4 + 3, all with literal slot indices
    for (int t = 0; t < 1020; t += 4) {
        STEP(t + 0, 0);
        STEP(t + 1, 1);
        STEP(t + 2, 2);
        STEP(t + 3, 3);
    }
    STEP(1020, 0);
    STEP(1021, 1);
    STEP(1022, 2);
#undef STEP
}

extern "C" void kernel_launch(void* const* d_in, const int* in_sizes, int n_in,
                              void* d_out, int out_size, void* d_ws, size_t ws_size,
                              hipStream_t stream) {
    const float* u    = (const float*)d_in[0];
    const float* rn   = (const float*)d_in[1];
    const float* inn  = (const float*)d_in[2];
    const float* Winp = (const float*)d_in[3];
    const float* Wrec = (const float*)d_in[4];
    const float* Wout = (const float*)d_in[5];

    float* states  = (float*)d_out;                          // 64*1024*1024
    float* outputs = (float*)d_out + (size_t)NN * TT * BB;   // 2*1024*1024

    latent_rnn<<<256, 256, 0, stream>>>(u, rn, inn, Winp, Wrec, Wout,
                                        states, outputs);
}